// Round 1
// baseline (1381.437 us; speedup 1.0000x reference)
//
#include <hip/hip_runtime.h>
#include <math.h>

#define HH 56
#define WS_W 56
#define HWS 3136
#define CD 384
#define BB 16
#define NROW (BB*HWS)                 // 50176
#define SLOT ((size_t)NROW*CD)        // 19267584 floats = 77 MB

// ---------------- DCT matrix (double precision host-free precompute) ----------
__global__ void prep_d_k(float* __restrict__ D) {
  for (int idx = threadIdx.x; idx < HH*HH; idx += blockDim.x) {
    int k = idx / HH, n = idx % HH;
    double v = cos(3.14159265358979323846 * (2.0*n + 1.0) * k / (2.0*HH)) * sqrt(2.0/HH);
    if (k == 0) v *= 0.70710678118654752440;
    D[idx] = (float)v;
  }
}

// ---------------- depthwise 3x3 conv + transpose to channel-last --------------
// grid (C/64, H, B), block 256. out xc[b, h*56+w, c]
__global__ __launch_bounds__(256) void conv_k(
    const float* __restrict__ x, const float* __restrict__ dww,
    const float* __restrict__ dwb, float* __restrict__ xc)
{
  __shared__ float xs[3][58][65];   // [dy][w+1 padded][ch], 65 pad kills bank conflicts
  __shared__ float wgt[64][9];
  __shared__ float wb[64];
  int t = threadIdx.x;
  int c0 = blockIdx.x * 64, h = blockIdx.y, b = blockIdx.z;
  for (int idx = t; idx < 64*3*56; idx += 256) {
    int ch = idx / 168, rem = idx % 168;
    int dy = rem / 56, w = rem % 56;
    int gh = h + dy - 1;
    float v = 0.f;
    if (gh >= 0 && gh < HH)
      v = x[(((size_t)b*CD + c0 + ch)*HH + gh)*WS_W + w];
    xs[dy][w+1][ch] = v;
  }
  for (int idx = t; idx < 64*3*2; idx += 256) {
    int ch = idx / 6, rem = idx % 6;
    int dy = rem / 2, e = rem % 2;
    xs[dy][e*57][ch] = 0.f;
  }
  for (int idx = t; idx < 64*9; idx += 256) {
    int ch = idx / 9, q = idx % 9;
    wgt[ch][q] = dww[(size_t)(c0+ch)*9 + q];
  }
  if (t < 64) wb[t] = dwb[c0 + t];
  __syncthreads();
  int ch = t & 63, wq = t >> 6;
  for (int wwi = 0; wwi < 14; ++wwi) {
    int w = wwi*4 + wq;
    float acc = wb[ch];
    #pragma unroll
    for (int dy = 0; dy < 3; ++dy)
      #pragma unroll
      for (int dx = 0; dx < 3; ++dx)
        acc = fmaf(wgt[ch][dy*3+dx], xs[dy][w+dx][ch], acc);
    xc[((size_t)b*HWS + h*WS_W + w)*CD + c0 + ch] = acc;
  }
}

// ---------------- tiled SGEMM: C[r,c] = sum_k A[r,k]*Bw[c,k]  (K=384) ---------
// EPI 0: +bias, split cols<384 -> out0 (xg), >=384 -> out1 (z)
// EPI 1: plain -> out0 (vel in freq domain)
// EPI 2: +bias, relu, -> cos/sin*decay maps (tok path)
// EPI 3: +bias, write d_out transposed to [B,C,H,W]
template<int EPI>
__global__ __launch_bounds__(256) void gemm_k(
    const float* __restrict__ A, const float* __restrict__ Bw,
    const float* __restrict__ bias, float* __restrict__ out0,
    float* __restrict__ out1, const float* __restrict__ cptr)
{
  __shared__ float As[16][68];
  __shared__ float Bs[16][68];
  int t = threadIdx.x;
  int col0 = blockIdx.x * 64;
  int row0 = blockIdx.y * 64;
  int lr = t >> 2, lk = (t & 3) * 4;
  const float* Ap = A + (size_t)(row0 + lr)*CD + lk;
  const float* Bp = Bw + (size_t)(col0 + lr)*CD + lk;
  float acc[4][4] = {};
  int tx = t & 15, ty = t >> 4;
  for (int k0 = 0; k0 < CD; k0 += 16) {
    float4 av = *(const float4*)(Ap + k0);
    float4 bv = *(const float4*)(Bp + k0);
    __syncthreads();
    As[lk+0][lr] = av.x; As[lk+1][lr] = av.y; As[lk+2][lr] = av.z; As[lk+3][lr] = av.w;
    Bs[lk+0][lr] = bv.x; Bs[lk+1][lr] = bv.y; Bs[lk+2][lr] = bv.z; Bs[lk+3][lr] = bv.w;
    __syncthreads();
    #pragma unroll
    for (int k = 0; k < 16; ++k) {
      float4 a4 = *(const float4*)&As[k][ty*4];
      float4 b4 = *(const float4*)&Bs[k][tx*4];
      float aa[4] = {a4.x, a4.y, a4.z, a4.w};
      float bbv[4] = {b4.x, b4.y, b4.z, b4.w};
      #pragma unroll
      for (int i = 0; i < 4; ++i)
        #pragma unroll
        for (int j = 0; j < 4; ++j)
          acc[i][j] = fmaf(aa[i], bbv[j], acc[i][j]);
    }
  }
  float cs = 0.f;
  if constexpr (EPI == 2) cs = cptr[0];
  #pragma unroll
  for (int i = 0; i < 4; ++i) {
    int r = row0 + ty*4 + i;
    #pragma unroll
    for (int j = 0; j < 4; ++j) {
      int cg = col0 + tx*4 + j;
      float v = acc[i][j];
      if constexpr (EPI == 0) {
        v += bias[cg];
        if (cg < CD) out0[(size_t)r*CD + cg] = v;
        else         out1[(size_t)r*CD + cg - CD] = v;
      } else if constexpr (EPI == 1) {
        out0[(size_t)r*CD + cg] = v;
      } else if constexpr (EPI == 2) {
        v += bias[cg];
        v = fmaxf(v, 0.f);
        int pi = r / 56, pj = r % 56;
        float wn = 3.14159265358979323846f/56.f * (float)pi;
        float wm = 3.14159265358979323846f/56.f * (float)pj;
        float dec = expf(-(wn*wn + wm*wm));
        out0[(size_t)r*CD + cg] = cosf(cs*v)*dec;
        out1[(size_t)r*CD + cg] = sinf(cs*v)/(cs + 1e-6f)*dec;
      } else {
        v += bias[cg];
        int bidx = r / HWS, hw = r % HWS;
        out0[((size_t)bidx*CD + cg)*HWS + hw] = v;
      }
    }
  }
}

// ---------------- batched 56x56 DCT-matrix apply: out[bt,m,:] = sum_k Dop[m,k] in[bt,k,:]
// trans=0: Dop=D ; trans=1: Dop=D^T.  grid (NC/128, BT), block 448 (14x32 threads, 4x4 tiles)
__global__ __launch_bounds__(448) void dct_k(
    const float* __restrict__ in, float* __restrict__ out,
    const float* __restrict__ D, int NC, int trans)
{
  __shared__ float Ds[56][60];   // Ds[k][m] = Dop[m][k]
  __shared__ float Xs[56][128];
  int t = threadIdx.x;
  int c0 = blockIdx.x * 128;
  size_t bt = blockIdx.y;
  for (int idx = t; idx < 3136; idx += 448) {
    int k = idx / 56, m = idx % 56;
    Ds[k][m] = trans ? D[k*56 + m] : D[m*56 + k];
  }
  const float* inb = in + bt*56*(size_t)NC + c0;
  for (int fi = t; fi < 56*32; fi += 448) {
    int rw = fi >> 5, cg = fi & 31;
    *(float4*)&Xs[rw][cg*4] = *(const float4*)(inb + (size_t)rw*NC + cg*4);
  }
  __syncthreads();
  int tx = t % 32, ty = t / 32;
  float acc[4][4] = {};
  #pragma unroll 4
  for (int k = 0; k < 56; ++k) {
    float4 a4 = *(const float4*)&Ds[k][ty*4];
    float4 b4 = *(const float4*)&Xs[k][tx*4];
    float aa[4] = {a4.x, a4.y, a4.z, a4.w};
    float bbv[4] = {b4.x, b4.y, b4.z, b4.w};
    #pragma unroll
    for (int i = 0; i < 4; ++i)
      #pragma unroll
      for (int j = 0; j < 4; ++j)
        acc[i][j] = fmaf(aa[i], bbv[j], acc[i][j]);
  }
  float* ob = out + bt*56*(size_t)NC + c0;
  #pragma unroll
  for (int i = 0; i < 4; ++i) {
    int m = ty*4 + i;
    float4 o; o.x = acc[i][0]; o.y = acc[i][1]; o.z = acc[i][2]; o.w = acc[i][3];
    *(float4*)(ob + (size_t)m*NC + tx*4) = o;
  }
}

// ---------------- modulation: F = cosD*U + sinD*(V + delta00*56*vel_b + 0.5*alpha*U)
__global__ __launch_bounds__(256) void mod_k(
    const float* __restrict__ U, float* __restrict__ V,
    const float* __restrict__ cosD, const float* __restrict__ sinD,
    const float* __restrict__ velb, const float* __restrict__ alphap)
{
  size_t i = ((size_t)blockIdx.x*blockDim.x + threadIdx.x)*4;
  if (i >= SLOT) return;
  float ah = alphap[0]*0.5f;
  size_t r = i / CD; int c = (int)(i % CD);
  int p = (int)(r % HWS);
  float4 u = *(const float4*)(U + i);
  float4 v = *(const float4*)(V + i);
  float4 cd = *(const float4*)(cosD + (size_t)p*CD + c);
  float4 sd = *(const float4*)(sinD + (size_t)p*CD + c);
  if (p == 0) {
    v.x += 56.f*velb[c];   v.y += 56.f*velb[c+1];
    v.z += 56.f*velb[c+2]; v.w += 56.f*velb[c+3];
  }
  float4 o;
  o.x = cd.x*u.x + sd.x*(v.x + ah*u.x);
  o.y = cd.y*u.y + sd.y*(v.y + ah*u.y);
  o.z = cd.z*u.z + sd.z*(v.z + ah*u.z);
  o.w = cd.w*u.w + sd.w*(v.w + ah*u.w);
  *(float4*)(V + i) = o;
}

// ---------------- LayerNorm over C + SiLU gate:  out = LN(y)*silu(z) ----------
__global__ __launch_bounds__(256) void ln_gate_k(
    const float* __restrict__ Y, const float* __restrict__ Z,
    const float* __restrict__ g, const float* __restrict__ be,
    float* __restrict__ out)
{
  int lane = threadIdx.x & 63, wv = threadIdx.x >> 6;
  size_t r = (size_t)blockIdx.x*4 + wv;
  const float* y = Y + r*CD;
  float v[6];
  float s = 0.f;
  #pragma unroll
  for (int q = 0; q < 6; ++q) { v[q] = y[lane + 64*q]; s += v[q]; }
  #pragma unroll
  for (int off = 32; off > 0; off >>= 1) s += __shfl_xor(s, off, 64);
  float mu = s * (1.f/384.f);
  float s2 = 0.f;
  #pragma unroll
  for (int q = 0; q < 6; ++q) { float d = v[q]-mu; s2 += d*d; }
  #pragma unroll
  for (int off = 32; off > 0; off >>= 1) s2 += __shfl_xor(s2, off, 64);
  float rs = 1.f / sqrtf(s2*(1.f/384.f) + 1e-5f);
  #pragma unroll
  for (int q = 0; q < 6; ++q) {
    int c = lane + 64*q;
    float yn = (v[q]-mu)*rs*g[c] + be[c];
    float zv = Z[r*CD + c];
    float sz = zv / (1.f + expf(-zv));
    out[r*CD + c] = yn*sz;
  }
}

extern "C" void kernel_launch(void* const* d_in, const int* in_sizes, int n_in,
                              void* d_out, int out_size, void* d_ws, size_t ws_size,
                              hipStream_t stream) {
  const float* x     = (const float*)d_in[0];
  const float* fe    = (const float*)d_in[1];
  const float* dw_w  = (const float*)d_in[2];
  const float* dw_b  = (const float*)d_in[3];
  const float* lin_w = (const float*)d_in[4];
  const float* lin_b = (const float*)d_in[5];
  const float* vel_w = (const float*)d_in[6];
  const float* vel_b = (const float*)d_in[7];
  const float* tok_w = (const float*)d_in[8];
  const float* tok_b = (const float*)d_in[9];
  const float* ln_g  = (const float*)d_in[10];
  const float* ln_b  = (const float*)d_in[11];
  const float* out_w = (const float*)d_in[12];
  const float* out_b = (const float*)d_in[13];
  const float* cp    = (const float*)d_in[14];
  const float* ap    = (const float*)d_in[15];

  float* ws    = (float*)d_ws;
  float* slotA = ws;                 // xc -> Tu -> V/F -> Y
  float* slotB = ws + SLOT;          // xg -> U  -> G -> gated
  float* slotC = ws + 2*SLOT;        // z
  float* Dm    = ws + 3*SLOT;
  float* cosD  = Dm + 3136;
  float* sinD  = cosD + (size_t)HWS*CD;

  prep_d_k<<<1, 256, 0, stream>>>(Dm);
  // conv(x) -> channel-last xc (slotA)
  conv_k<<<dim3(6, 56, 16), 256, 0, stream>>>(x, dw_w, dw_b, slotA);
  // tok path: cos/sin*decay maps
  gemm_k<2><<<dim3(6, 49), 256, 0, stream>>>(fe, tok_w, tok_b, cosD, sinD, cp);
  // lin: xz = xc @ lin_w^T + lin_b -> xg (slotB), z (slotC)
  gemm_k<0><<<dim3(12, 784), 256, 0, stream>>>(slotA, lin_w, lin_b, slotB, slotC, nullptr);
  // forward DCT: Tu = D @ xg (rows=h), then U = D applied over w
  dct_k<<<dim3(168, 16), 448, 0, stream>>>(slotB, slotA, Dm, 21504, 0); // Tu -> slotA
  dct_k<<<dim3(3, 896), 448, 0, stream>>>(slotA, slotB, Dm, 384, 0);    // U  -> slotB
  // vel in frequency domain: V = U @ vel_w^T  (bias handled as delta at (0,0))
  gemm_k<1><<<dim3(6, 784), 256, 0, stream>>>(slotB, vel_w, nullptr, slotA, nullptr, nullptr);
  // modulation (writes F in place of V, slotA)
  mod_k<<<18816, 256, 0, stream>>>(slotB, slotA, cosD, sinD, vel_b, ap);
  // inverse DCT (D^T): G = D^T @ F over p, then Y over q
  dct_k<<<dim3(168, 16), 448, 0, stream>>>(slotA, slotB, Dm, 21504, 1); // G -> slotB
  dct_k<<<dim3(3, 896), 448, 0, stream>>>(slotB, slotA, Dm, 384, 1);    // Y -> slotA
  // LayerNorm + SiLU gate -> gated (slotB)
  ln_gate_k<<<12544, 256, 0, stream>>>(slotA, slotC, ln_g, ln_b, slotB);
  // out GEMM -> d_out [B,C,H,W]
  gemm_k<3><<<dim3(6, 784), 256, 0, stream>>>(slotB, out_w, out_b, (float*)d_out, nullptr, nullptr);
}

// Round 2
// 895.868 us; speedup vs baseline: 1.5420x; 1.5420x over previous
//
#include <hip/hip_runtime.h>
#include <math.h>

#define HH 56
#define WS_W 56
#define HWS 3136
#define CD 384
#define BB 16
#define NROW (BB*HWS)                 // 50176
#define SLOT ((size_t)NROW*CD)        // 19267584 floats = 77 MB

typedef __attribute__((ext_vector_type(8))) short bf16x8;
typedef __attribute__((ext_vector_type(4))) float f32x4;

__device__ inline ushort f2bf(float v) {
  uint u = __float_as_uint(v);
  uint r = (u + 0x7fffu + ((u >> 16) & 1u)) >> 16;
  return (ushort)r;
}
__device__ inline float bf2f(ushort h) { return __uint_as_float((uint)h << 16); }

__device__ inline void split_octet(const float* f, uint4& hi, uint4& lo) {
  ushort hs[8], ls[8];
  #pragma unroll
  for (int i = 0; i < 8; ++i) {
    float v = f[i];
    ushort h = f2bf(v);
    hs[i] = h;
    ls[i] = f2bf(v - bf2f(h));
  }
  hi.x = hs[0] | ((uint)hs[1] << 16); hi.y = hs[2] | ((uint)hs[3] << 16);
  hi.z = hs[4] | ((uint)hs[5] << 16); hi.w = hs[6] | ((uint)hs[7] << 16);
  lo.x = ls[0] | ((uint)ls[1] << 16); lo.y = ls[2] | ((uint)ls[3] << 16);
  lo.z = ls[4] | ((uint)ls[5] << 16); lo.w = ls[6] | ((uint)ls[7] << 16);
}

// ---------------- DCT matrix ----------
__global__ void prep_d_k(float* __restrict__ D) {
  for (int idx = threadIdx.x; idx < HH*HH; idx += blockDim.x) {
    int k = idx / HH, n = idx % HH;
    double v = cos(3.14159265358979323846 * (2.0*n + 1.0) * k / (2.0*HH)) * sqrt(2.0/HH);
    if (k == 0) v *= 0.70710678118654752440;
    D[idx] = (float)v;
  }
}

// ---------------- weight split fp32 -> bf16 hi/lo ----------------
__global__ __launch_bounds__(256) void split_w_k(
    const float* __restrict__ W, ushort* __restrict__ hi,
    ushort* __restrict__ lo, int nelem) {
  int i = blockIdx.x*256 + threadIdx.x;
  if (i >= nelem) return;
  float v = W[i];
  ushort h = f2bf(v);
  hi[i] = h;
  lo[i] = f2bf(v - bf2f(h));
}

// ---------------- depthwise 3x3 conv + transpose to channel-last --------------
__global__ __launch_bounds__(256) void conv_k(
    const float* __restrict__ x, const float* __restrict__ dww,
    const float* __restrict__ dwb, float* __restrict__ xc)
{
  __shared__ float xs[3][58][65];
  __shared__ float wgt[64][9];
  __shared__ float wb[64];
  int t = threadIdx.x;
  int c0 = blockIdx.x * 64, h = blockIdx.y, b = blockIdx.z;
  for (int idx = t; idx < 64*3*56; idx += 256) {
    int ch = idx / 168, rem = idx % 168;
    int dy = rem / 56, w = rem % 56;
    int gh = h + dy - 1;
    float v = 0.f;
    if (gh >= 0 && gh < HH)
      v = x[(((size_t)b*CD + c0 + ch)*HH + gh)*WS_W + w];
    xs[dy][w+1][ch] = v;
  }
  for (int idx = t; idx < 64*3*2; idx += 256) {
    int ch = idx / 6, rem = idx % 6;
    int dy = rem / 2, e = rem % 2;
    xs[dy][e*57][ch] = 0.f;
  }
  for (int idx = t; idx < 64*9; idx += 256) {
    int ch = idx / 9, q = idx % 9;
    wgt[ch][q] = dww[(size_t)(c0+ch)*9 + q];
  }
  if (t < 64) wb[t] = dwb[c0 + t];
  __syncthreads();
  int ch = t & 63, wq = t >> 6;
  for (int wwi = 0; wwi < 14; ++wwi) {
    int w = wwi*4 + wq;
    float acc = wb[ch];
    #pragma unroll
    for (int dy = 0; dy < 3; ++dy)
      #pragma unroll
      for (int dx = 0; dx < 3; ++dx)
        acc = fmaf(wgt[ch][dy*3+dx], xs[dy][w+dx][ch], acc);
    xc[((size_t)b*HWS + h*WS_W + w)*CD + c0 + ch] = acc;
  }
}

// ---------------- fp32 tiled GEMM (kept for tok path only, EPI 2) ---------
template<int EPI>
__global__ __launch_bounds__(256) void gemm_k(
    const float* __restrict__ A, const float* __restrict__ Bw,
    const float* __restrict__ bias, float* __restrict__ out0,
    float* __restrict__ out1, const float* __restrict__ cptr)
{
  __shared__ float As[16][68];
  __shared__ float Bs[16][68];
  int t = threadIdx.x;
  int col0 = blockIdx.x * 64;
  int row0 = blockIdx.y * 64;
  int lr = t >> 2, lk = (t & 3) * 4;
  const float* Ap = A + (size_t)(row0 + lr)*CD + lk;
  const float* Bp = Bw + (size_t)(col0 + lr)*CD + lk;
  float acc[4][4] = {};
  int tx = t & 15, ty = t >> 4;
  for (int k0 = 0; k0 < CD; k0 += 16) {
    float4 av = *(const float4*)(Ap + k0);
    float4 bv = *(const float4*)(Bp + k0);
    __syncthreads();
    As[lk+0][lr] = av.x; As[lk+1][lr] = av.y; As[lk+2][lr] = av.z; As[lk+3][lr] = av.w;
    Bs[lk+0][lr] = bv.x; Bs[lk+1][lr] = bv.y; Bs[lk+2][lr] = bv.z; Bs[lk+3][lr] = bv.w;
    __syncthreads();
    #pragma unroll
    for (int k = 0; k < 16; ++k) {
      float4 a4 = *(const float4*)&As[k][ty*4];
      float4 b4 = *(const float4*)&Bs[k][tx*4];
      float aa[4] = {a4.x, a4.y, a4.z, a4.w};
      float bbv[4] = {b4.x, b4.y, b4.z, b4.w};
      #pragma unroll
      for (int i = 0; i < 4; ++i)
        #pragma unroll
        for (int j = 0; j < 4; ++j)
          acc[i][j] = fmaf(aa[i], bbv[j], acc[i][j]);
    }
  }
  float cs = 0.f;
  if constexpr (EPI == 2) cs = cptr[0];
  #pragma unroll
  for (int i = 0; i < 4; ++i) {
    int r = row0 + ty*4 + i;
    #pragma unroll
    for (int j = 0; j < 4; ++j) {
      int cg = col0 + tx*4 + j;
      float v = acc[i][j];
      if constexpr (EPI == 2) {
        v += bias[cg];
        v = fmaxf(v, 0.f);
        int pi = r / 56, pj = r % 56;
        float wn = 3.14159265358979323846f/56.f * (float)pi;
        float wm = 3.14159265358979323846f/56.f * (float)pj;
        float dec = expf(-(wn*wn + wm*wm));
        out0[(size_t)r*CD + cg] = cosf(cs*v)*dec;
        out1[(size_t)r*CD + cg] = sinf(cs*v)/(cs + 1e-6f)*dec;
      }
    }
  }
}

// ---------------- split-bf16 MFMA GEMM: C = A @ W^T ------------------------
// A fp32 [M,384] converted to hi/lo bf16 in staging. W pre-split bf16 hi/lo.
// tile 128x128, 256 threads, wave -> 64x64 (4x4 mfma_16x16x32 tiles).
// EPI 0: +bias, split cols -> out0 (xg), out1 (z)
// EPI 1: vel + fused modulation epilogue -> out0 = F
// EPI 3: +bias, transposed write to d_out [B,C,H,W]
template<int EPI>
__global__ __launch_bounds__(256, 2) void mgemm_k(
    const float* __restrict__ A, const ushort* __restrict__ Wh,
    const ushort* __restrict__ Wl, const float* __restrict__ bias,
    float* __restrict__ out0, float* __restrict__ out1,
    const float* __restrict__ Uin, const float* __restrict__ cosD,
    const float* __restrict__ sinD, const float* __restrict__ velb,
    const float* __restrict__ alphap)
{
  // LDS layout (bytes): Ah[0,8K) Al[8K,16K) Bh[16K,24K) Bl[24K,32K)
  // each region: 8 sub-tiles (16 rows x 32 k) x 1 KiB, fragment-ordered:
  // sub-tile st, piece (q,n) at st*1024 + (q*16+n)*16  == lane-contiguous.
  __shared__ char smem[32768];
  int t = threadIdx.x;
  int col0 = blockIdx.x * 128, row0 = blockIdx.y * 128;
  int r = t >> 1, half = t & 1;
  int n = r & 15, rt = r >> 4, q0 = half * 2;
  const float*  Ap  = A  + (size_t)(row0 + r)*CD + half*16;
  const ushort* Bhp = Wh + (size_t)(col0 + r)*CD + half*16;
  const ushort* Blp = Wl + (size_t)(col0 + r)*CD + half*16;
  int aoff0 = rt*1024 + (q0*16 + n)*16;
  int aoff1 = rt*1024 + ((q0+1)*16 + n)*16;
  int boff0 = 16384 + aoff0, boff1 = 16384 + aoff1;
  int wid = t >> 6, lane = t & 63;
  int wr = wid >> 1, wc = wid & 1;
  f32x4 acc[4][4];
  #pragma unroll
  for (int i = 0; i < 4; ++i)
    #pragma unroll
    for (int j = 0; j < 4; ++j)
      acc[i][j] = (f32x4){0.f, 0.f, 0.f, 0.f};

  for (int k0 = 0; k0 < CD; k0 += 32) {
    float4 f0 = *(const float4*)(Ap + k0);
    float4 f1 = *(const float4*)(Ap + k0 + 4);
    float4 f2 = *(const float4*)(Ap + k0 + 8);
    float4 f3 = *(const float4*)(Ap + k0 + 12);
    uint4 bh0 = *(const uint4*)(Bhp + k0);
    uint4 bh1 = *(const uint4*)(Bhp + k0 + 8);
    uint4 bl0 = *(const uint4*)(Blp + k0);
    uint4 bl1 = *(const uint4*)(Blp + k0 + 8);
    __syncthreads();
    float fa[16] = {f0.x,f0.y,f0.z,f0.w, f1.x,f1.y,f1.z,f1.w,
                    f2.x,f2.y,f2.z,f2.w, f3.x,f3.y,f3.z,f3.w};
    uint4 ah0, al0, ah1, al1;
    split_octet(&fa[0], ah0, al0);
    split_octet(&fa[8], ah1, al1);
    *(uint4*)(smem + aoff0)        = ah0;
    *(uint4*)(smem + aoff0 + 8192) = al0;
    *(uint4*)(smem + aoff1)        = ah1;
    *(uint4*)(smem + aoff1 + 8192) = al1;
    *(uint4*)(smem + boff0)        = bh0;
    *(uint4*)(smem + boff0 + 8192) = bl0;
    *(uint4*)(smem + boff1)        = bh1;
    *(uint4*)(smem + boff1 + 8192) = bl1;
    __syncthreads();
    bf16x8 Ah[4], Al[4], Bh[4], Bl[4];
    #pragma unroll
    for (int i = 0; i < 4; ++i) {
      int ao = (wr*4 + i)*1024 + lane*16;
      Ah[i] = *(const bf16x8*)(smem + ao);
      Al[i] = *(const bf16x8*)(smem + ao + 8192);
      int bo = 16384 + (wc*4 + i)*1024 + lane*16;
      Bh[i] = *(const bf16x8*)(smem + bo);
      Bl[i] = *(const bf16x8*)(smem + bo + 8192);
    }
    #pragma unroll
    for (int i = 0; i < 4; ++i)
      #pragma unroll
      for (int j = 0; j < 4; ++j) {
        acc[i][j] = __builtin_amdgcn_mfma_f32_16x16x32_bf16(Ah[i], Bh[j], acc[i][j], 0, 0, 0);
        acc[i][j] = __builtin_amdgcn_mfma_f32_16x16x32_bf16(Ah[i], Bl[j], acc[i][j], 0, 0, 0);
        acc[i][j] = __builtin_amdgcn_mfma_f32_16x16x32_bf16(Al[i], Bh[j], acc[i][j], 0, 0, 0);
      }
  }

  int nn = lane & 15, qq = lane >> 4;
  float ahalf = 0.f;
  if constexpr (EPI == 1) ahalf = 0.5f * alphap[0];
  #pragma unroll
  for (int i = 0; i < 4; ++i) {
    #pragma unroll
    for (int j = 0; j < 4; ++j) {
      #pragma unroll
      for (int reg = 0; reg < 4; ++reg) {
        int rg = row0 + wr*64 + i*16 + qq*4 + reg;
        int cg = col0 + wc*64 + j*16 + nn;
        float v = acc[i][j][reg];
        if constexpr (EPI == 0) {
          v += bias[cg];
          if (cg < CD) out0[(size_t)rg*CD + cg] = v;
          else         out1[(size_t)rg*CD + cg - CD] = v;
        } else if constexpr (EPI == 1) {
          int p = rg % HWS;
          float u  = Uin[(size_t)rg*CD + cg];
          float cd = cosD[(size_t)p*CD + cg];
          float sd = sinD[(size_t)p*CD + cg];
          if (p == 0) v += 56.f * velb[cg];
          out0[(size_t)rg*CD + cg] = cd*u + sd*(v + ahalf*u);
        } else {
          v += bias[cg];
          int bidx = rg / HWS, hw = rg % HWS;
          out0[((size_t)bidx*CD + cg)*HWS + hw] = v;
        }
      }
    }
  }
}

// ---------------- batched 56x56 DCT-matrix apply ------------------------------
__global__ __launch_bounds__(448) void dct_k(
    const float* __restrict__ in, float* __restrict__ out,
    const float* __restrict__ D, int NC, int trans)
{
  __shared__ float Ds[56][60];
  __shared__ float Xs[56][128];
  int t = threadIdx.x;
  int c0 = blockIdx.x * 128;
  size_t bt = blockIdx.y;
  for (int idx = t; idx < 3136; idx += 448) {
    int k = idx / 56, m = idx % 56;
    Ds[k][m] = trans ? D[k*56 + m] : D[m*56 + k];
  }
  const float* inb = in + bt*56*(size_t)NC + c0;
  for (int fi = t; fi < 56*32; fi += 448) {
    int rw = fi >> 5, cg = fi & 31;
    *(float4*)&Xs[rw][cg*4] = *(const float4*)(inb + (size_t)rw*NC + cg*4);
  }
  __syncthreads();
  int tx = t % 32, ty = t / 32;
  float acc[4][4] = {};
  #pragma unroll 4
  for (int k = 0; k < 56; ++k) {
    float4 a4 = *(const float4*)&Ds[k][ty*4];
    float4 b4 = *(const float4*)&Xs[k][tx*4];
    float aa[4] = {a4.x, a4.y, a4.z, a4.w};
    float bbv[4] = {b4.x, b4.y, b4.z, b4.w};
    #pragma unroll
    for (int i = 0; i < 4; ++i)
      #pragma unroll
      for (int j = 0; j < 4; ++j)
        acc[i][j] = fmaf(aa[i], bbv[j], acc[i][j]);
  }
  float* ob = out + bt*56*(size_t)NC + c0;
  #pragma unroll
  for (int i = 0; i < 4; ++i) {
    int m = ty*4 + i;
    float4 o; o.x = acc[i][0]; o.y = acc[i][1]; o.z = acc[i][2]; o.w = acc[i][3];
    *(float4*)(ob + (size_t)m*NC + tx*4) = o;
  }
}

// ---------------- LayerNorm over C + SiLU gate --------------------------------
__global__ __launch_bounds__(256) void ln_gate_k(
    const float* __restrict__ Y, const float* __restrict__ Z,
    const float* __restrict__ g, const float* __restrict__ be,
    float* __restrict__ out)
{
  int lane = threadIdx.x & 63, wv = threadIdx.x >> 6;
  size_t r = (size_t)blockIdx.x*4 + wv;
  const float* y = Y + r*CD;
  float v[6];
  float s = 0.f;
  #pragma unroll
  for (int q = 0; q < 6; ++q) { v[q] = y[lane + 64*q]; s += v[q]; }
  #pragma unroll
  for (int off = 32; off > 0; off >>= 1) s += __shfl_xor(s, off, 64);
  float mu = s * (1.f/384.f);
  float s2 = 0.f;
  #pragma unroll
  for (int q = 0; q < 6; ++q) { float d = v[q]-mu; s2 += d*d; }
  #pragma unroll
  for (int off = 32; off > 0; off >>= 1) s2 += __shfl_xor(s2, off, 64);
  float rs = 1.f / sqrtf(s2*(1.f/384.f) + 1e-5f);
  #pragma unroll
  for (int q = 0; q < 6; ++q) {
    int c = lane + 64*q;
    float yn = (v[q]-mu)*rs*g[c] + be[c];
    float zv = Z[r*CD + c];
    float sz = zv / (1.f + expf(-zv));
    out[r*CD + c] = yn*sz;
  }
}

extern "C" void kernel_launch(void* const* d_in, const int* in_sizes, int n_in,
                              void* d_out, int out_size, void* d_ws, size_t ws_size,
                              hipStream_t stream) {
  const float* x     = (const float*)d_in[0];
  const float* fe    = (const float*)d_in[1];
  const float* dw_w  = (const float*)d_in[2];
  const float* dw_b  = (const float*)d_in[3];
  const float* lin_w = (const float*)d_in[4];
  const float* lin_b = (const float*)d_in[5];
  const float* vel_w = (const float*)d_in[6];
  const float* vel_b = (const float*)d_in[7];
  const float* tok_w = (const float*)d_in[8];
  const float* tok_b = (const float*)d_in[9];
  const float* ln_g  = (const float*)d_in[10];
  const float* ln_b  = (const float*)d_in[11];
  const float* out_w = (const float*)d_in[12];
  const float* out_b = (const float*)d_in[13];
  const float* cp    = (const float*)d_in[14];
  const float* ap    = (const float*)d_in[15];

  float* ws    = (float*)d_ws;
  float* slotA = ws;                 // xc -> Tu -> F -> Y
  float* slotB = ws + SLOT;          // xg -> U -> G -> gated
  float* slotC = ws + 2*SLOT;        // z
  float* Dm    = ws + 3*SLOT;
  float* cosD  = Dm + 3136;
  float* sinD  = cosD + (size_t)HWS*CD;
  ushort* whi  = (ushort*)(sinD + (size_t)HWS*CD);
  ushort* wlo  = whi + 589824;
  // weight split offsets (elements): lin 0, vel 294912, out 442368

  prep_d_k<<<1, 256, 0, stream>>>(Dm);
  split_w_k<<<1152, 256, 0, stream>>>(lin_w, whi,          wlo,          294912);
  split_w_k<<< 576, 256, 0, stream>>>(vel_w, whi + 294912, wlo + 294912, 147456);
  split_w_k<<< 576, 256, 0, stream>>>(out_w, whi + 442368, wlo + 442368, 147456);

  // conv(x) -> channel-last xc (slotA)
  conv_k<<<dim3(6, 56, 16), 256, 0, stream>>>(x, dw_w, dw_b, slotA);
  // tok path: cos/sin*decay maps
  gemm_k<2><<<dim3(6, 49), 256, 0, stream>>>(fe, tok_w, tok_b, cosD, sinD, cp);
  // lin: xz = xc @ lin_w^T + lin_b -> xg (slotB), z (slotC)
  mgemm_k<0><<<dim3(6, 392), 256, 0, stream>>>(slotA, whi, wlo, lin_b,
      slotB, slotC, nullptr, nullptr, nullptr, nullptr, nullptr);
  // forward DCT
  dct_k<<<dim3(168, 16), 448, 0, stream>>>(slotB, slotA, Dm, 21504, 0); // Tu -> slotA
  dct_k<<<dim3(3, 896), 448, 0, stream>>>(slotA, slotB, Dm, 384, 0);    // U  -> slotB
  // vel in freq domain + fused modulation -> F (slotA)
  mgemm_k<1><<<dim3(3, 392), 256, 0, stream>>>(slotB, whi + 294912, wlo + 294912,
      nullptr, slotA, nullptr, slotB, cosD, sinD, vel_b, ap);
  // inverse DCT
  dct_k<<<dim3(168, 16), 448, 0, stream>>>(slotA, slotB, Dm, 21504, 1); // G -> slotB
  dct_k<<<dim3(3, 896), 448, 0, stream>>>(slotB, slotA, Dm, 384, 1);    // Y -> slotA
  // LayerNorm + SiLU gate -> gated (slotB)
  ln_gate_k<<<12544, 256, 0, stream>>>(slotA, slotC, ln_g, ln_b, slotB);
  // out GEMM -> d_out [B,C,H,W]
  mgemm_k<3><<<dim3(3, 392), 256, 0, stream>>>(slotB, whi + 442368, wlo + 442368,
      out_b, (float*)d_out, nullptr, nullptr, nullptr, nullptr, nullptr, nullptr);
}

// Round 4
// 749.598 us; speedup vs baseline: 1.8429x; 1.1951x over previous
//
#include <hip/hip_runtime.h>
#include <math.h>

#define HH 56
#define WS_W 56
#define HWS 3136
#define CD 384
#define BB 16
#define NROW (BB*HWS)                 // 50176
#define SLOT ((size_t)NROW*CD)        // 19267584 floats = 77 MB

typedef __attribute__((ext_vector_type(8))) short bf16x8;
typedef __attribute__((ext_vector_type(4))) float f32x4;

__device__ inline ushort f2bf(float v) {
  uint u = __float_as_uint(v);
  uint r = (u + 0x7fffu + ((u >> 16) & 1u)) >> 16;
  return (ushort)r;
}
__device__ inline float bf2f(ushort h) { return __uint_as_float((uint)h << 16); }

__device__ inline void split_octet(const float* f, uint4& hi, uint4& lo) {
  ushort hs[8], ls[8];
  #pragma unroll
  for (int i = 0; i < 8; ++i) {
    float v = f[i];
    ushort h = f2bf(v);
    hs[i] = h;
    ls[i] = f2bf(v - bf2f(h));
  }
  hi.x = hs[0] | ((uint)hs[1] << 16); hi.y = hs[2] | ((uint)hs[3] << 16);
  hi.z = hs[4] | ((uint)hs[5] << 16); hi.w = hs[6] | ((uint)hs[7] << 16);
  lo.x = ls[0] | ((uint)ls[1] << 16); lo.y = ls[2] | ((uint)ls[3] << 16);
  lo.z = ls[4] | ((uint)ls[5] << 16); lo.w = ls[6] | ((uint)ls[7] << 16);
}

// ---------------- DCT matrix ----------
__global__ void prep_d_k(float* __restrict__ D) {
  for (int idx = threadIdx.x; idx < HH*HH; idx += blockDim.x) {
    int k = idx / HH, n = idx % HH;
    double v = cos(3.14159265358979323846 * (2.0*n + 1.0) * k / (2.0*HH)) * sqrt(2.0/HH);
    if (k == 0) v *= 0.70710678118654752440;
    D[idx] = (float)v;
  }
}

// ---------------- weight split fp32 -> bf16 hi/lo ----------------
__global__ __launch_bounds__(256) void split_w_k(
    const float* __restrict__ W, ushort* __restrict__ hi,
    ushort* __restrict__ lo, int nelem) {
  int i = blockIdx.x*256 + threadIdx.x;
  if (i >= nelem) return;
  float v = W[i];
  ushort h = f2bf(v);
  hi[i] = h;
  lo[i] = f2bf(v - bf2f(h));
}

// ---------------- depthwise 3x3 conv + transpose to channel-last --------------
// grid (12, 56, 16), block 256; 32 channels per block. 23 KB LDS -> 6 blocks/CU.
__global__ __launch_bounds__(256) void conv_k(
    const float* __restrict__ x, const float* __restrict__ dww,
    const float* __restrict__ dwb, float* __restrict__ xc)
{
  __shared__ float xs[3][58][33];   // [dy][w+1][ch], 33 pad: 2 lanes/bank reads
  __shared__ float wgt[32][9];
  __shared__ float wb[32];
  int t = threadIdx.x;
  int c0 = blockIdx.x * 32, h = blockIdx.y, b = blockIdx.z;
  // staging: 32 ch x 3 dy x 14 float4 = 1344 units, 5.25/thread
  for (int idx = t; idx < 1344; idx += 256) {
    int wq = idx % 14, rem = idx / 14;
    int dy = rem % 3, ch = rem / 3;
    int gh = h + dy - 1;
    float4 v = {0.f, 0.f, 0.f, 0.f};
    if (gh >= 0 && gh < HH)
      v = *(const float4*)(x + (((size_t)b*CD + c0 + ch)*HH + gh)*WS_W + wq*4);
    int wp = wq*4 + 1;
    xs[dy][wp+0][ch] = v.x;
    xs[dy][wp+1][ch] = v.y;
    xs[dy][wp+2][ch] = v.z;
    xs[dy][wp+3][ch] = v.w;
  }
  if (t < 192) {        // halo zeros: 32 ch x 3 dy x 2 edges
    int e = t & 1, dy = (t >> 1) % 3, ch = t / 6;
    xs[dy][e*57][ch] = 0.f;
  }
  for (int idx = t; idx < 288; idx += 256)   // FIX: 288 > blockDim, must loop
    wgt[idx/9][idx%9] = dww[(size_t)(c0 + idx/9)*9 + idx%9];
  if (t < 32) wb[t] = dwb[c0 + t];
  __syncthreads();
  int ch = t & 31, wq8 = t >> 5;    // 8 w-positions per pass
  #pragma unroll
  for (int wwi = 0; wwi < 7; ++wwi) {
    int w = wwi*8 + wq8;
    float acc = wb[ch];
    #pragma unroll
    for (int dy = 0; dy < 3; ++dy)
      #pragma unroll
      for (int dx = 0; dx < 3; ++dx)
        acc = fmaf(wgt[ch][dy*3+dx], xs[dy][w+dx][ch], acc);
    xc[((size_t)b*HWS + h*WS_W + w)*CD + c0 + ch] = acc;
  }
}

// ---------------- fp32 tiled GEMM (tok path only, EPI 2) ---------
template<int EPI>
__global__ __launch_bounds__(256) void gemm_k(
    const float* __restrict__ A, const float* __restrict__ Bw,
    const float* __restrict__ bias, float* __restrict__ out0,
    float* __restrict__ out1, const float* __restrict__ cptr)
{
  __shared__ float As[16][68];
  __shared__ float Bs[16][68];
  int t = threadIdx.x;
  int col0 = blockIdx.x * 64;
  int row0 = blockIdx.y * 64;
  int lr = t >> 2, lk = (t & 3) * 4;
  const float* Ap = A + (size_t)(row0 + lr)*CD + lk;
  const float* Bp = Bw + (size_t)(col0 + lr)*CD + lk;
  float acc[4][4] = {};
  int tx = t & 15, ty = t >> 4;
  for (int k0 = 0; k0 < CD; k0 += 16) {
    float4 av = *(const float4*)(Ap + k0);
    float4 bv = *(const float4*)(Bp + k0);
    __syncthreads();
    As[lk+0][lr] = av.x; As[lk+1][lr] = av.y; As[lk+2][lr] = av.z; As[lk+3][lr] = av.w;
    Bs[lk+0][lr] = bv.x; Bs[lk+1][lr] = bv.y; Bs[lk+2][lr] = bv.z; Bs[lk+3][lr] = bv.w;
    __syncthreads();
    #pragma unroll
    for (int k = 0; k < 16; ++k) {
      float4 a4 = *(const float4*)&As[k][ty*4];
      float4 b4 = *(const float4*)&Bs[k][tx*4];
      float aa[4] = {a4.x, a4.y, a4.z, a4.w};
      float bbv[4] = {b4.x, b4.y, b4.z, b4.w};
      #pragma unroll
      for (int i = 0; i < 4; ++i)
        #pragma unroll
        for (int j = 0; j < 4; ++j)
          acc[i][j] = fmaf(aa[i], bbv[j], acc[i][j]);
    }
  }
  float cs = 0.f;
  if constexpr (EPI == 2) cs = cptr[0];
  #pragma unroll
  for (int i = 0; i < 4; ++i) {
    int r = row0 + ty*4 + i;
    #pragma unroll
    for (int j = 0; j < 4; ++j) {
      int cg = col0 + tx*4 + j;
      float v = acc[i][j];
      if constexpr (EPI == 2) {
        v += bias[cg];
        v = fmaxf(v, 0.f);
        int pi = r / 56, pj = r % 56;
        float wn = 3.14159265358979323846f/56.f * (float)pi;
        float wm = 3.14159265358979323846f/56.f * (float)pj;
        float dec = expf(-(wn*wn + wm*wm));
        out0[(size_t)r*CD + cg] = cosf(cs*v)*dec;
        out1[(size_t)r*CD + cg] = sinf(cs*v)/(cs + 1e-6f)*dec;
      }
    }
  }
}

// ---------------- split-bf16 MFMA GEMM: C = A @ W^T ------------------------
template<int EPI>
__global__ __launch_bounds__(256, 2) void mgemm_k(
    const float* __restrict__ A, const ushort* __restrict__ Wh,
    const ushort* __restrict__ Wl, const float* __restrict__ bias,
    float* __restrict__ out0, float* __restrict__ out1,
    const float* __restrict__ Uin, const float* __restrict__ cosD,
    const float* __restrict__ sinD, const float* __restrict__ velb,
    const float* __restrict__ alphap)
{
  __shared__ char smem[32768];
  int t = threadIdx.x;
  int col0 = blockIdx.x * 128, row0 = blockIdx.y * 128;
  int r = t >> 1, half = t & 1;
  int n = r & 15, rt = r >> 4, q0 = half * 2;
  const float*  Ap  = A  + (size_t)(row0 + r)*CD + half*16;
  const ushort* Bhp = Wh + (size_t)(col0 + r)*CD + half*16;
  const ushort* Blp = Wl + (size_t)(col0 + r)*CD + half*16;
  int aoff0 = rt*1024 + (q0*16 + n)*16;
  int aoff1 = rt*1024 + ((q0+1)*16 + n)*16;
  int boff0 = 16384 + aoff0, boff1 = 16384 + aoff1;
  int wid = t >> 6, lane = t & 63;
  int wr = wid >> 1, wc = wid & 1;
  f32x4 acc[4][4];
  #pragma unroll
  for (int i = 0; i < 4; ++i)
    #pragma unroll
    for (int j = 0; j < 4; ++j)
      acc[i][j] = (f32x4){0.f, 0.f, 0.f, 0.f};

  for (int k0 = 0; k0 < CD; k0 += 32) {
    float4 f0 = *(const float4*)(Ap + k0);
    float4 f1 = *(const float4*)(Ap + k0 + 4);
    float4 f2 = *(const float4*)(Ap + k0 + 8);
    float4 f3 = *(const float4*)(Ap + k0 + 12);
    uint4 bh0 = *(const uint4*)(Bhp + k0);
    uint4 bh1 = *(const uint4*)(Bhp + k0 + 8);
    uint4 bl0 = *(const uint4*)(Blp + k0);
    uint4 bl1 = *(const uint4*)(Blp + k0 + 8);
    __syncthreads();
    float fa[16] = {f0.x,f0.y,f0.z,f0.w, f1.x,f1.y,f1.z,f1.w,
                    f2.x,f2.y,f2.z,f2.w, f3.x,f3.y,f3.z,f3.w};
    uint4 ah0, al0, ah1, al1;
    split_octet(&fa[0], ah0, al0);
    split_octet(&fa[8], ah1, al1);
    *(uint4*)(smem + aoff0)        = ah0;
    *(uint4*)(smem + aoff0 + 8192) = al0;
    *(uint4*)(smem + aoff1)        = ah1;
    *(uint4*)(smem + aoff1 + 8192) = al1;
    *(uint4*)(smem + boff0)        = bh0;
    *(uint4*)(smem + boff0 + 8192) = bl0;
    *(uint4*)(smem + boff1)        = bh1;
    *(uint4*)(smem + boff1 + 8192) = bl1;
    __syncthreads();
    bf16x8 Ah[4], Al[4], Bh[4], Bl[4];
    #pragma unroll
    for (int i = 0; i < 4; ++i) {
      int ao = (wr*4 + i)*1024 + lane*16;
      Ah[i] = *(const bf16x8*)(smem + ao);
      Al[i] = *(const bf16x8*)(smem + ao + 8192);
      int bo = 16384 + (wc*4 + i)*1024 + lane*16;
      Bh[i] = *(const bf16x8*)(smem + bo);
      Bl[i] = *(const bf16x8*)(smem + bo + 8192);
    }
    #pragma unroll
    for (int i = 0; i < 4; ++i)
      #pragma unroll
      for (int j = 0; j < 4; ++j) {
        acc[i][j] = __builtin_amdgcn_mfma_f32_16x16x32_bf16(Ah[i], Bh[j], acc[i][j], 0, 0, 0);
        acc[i][j] = __builtin_amdgcn_mfma_f32_16x16x32_bf16(Ah[i], Bl[j], acc[i][j], 0, 0, 0);
        acc[i][j] = __builtin_amdgcn_mfma_f32_16x16x32_bf16(Al[i], Bh[j], acc[i][j], 0, 0, 0);
      }
  }

  int nn = lane & 15, qq = lane >> 4;
  float ahalf = 0.f;
  if constexpr (EPI == 1) ahalf = 0.5f * alphap[0];
  #pragma unroll
  for (int i = 0; i < 4; ++i) {
    #pragma unroll
    for (int j = 0; j < 4; ++j) {
      #pragma unroll
      for (int reg = 0; reg < 4; ++reg) {
        int rg = row0 + wr*64 + i*16 + qq*4 + reg;
        int cg = col0 + wc*64 + j*16 + nn;
        float v = acc[i][j][reg];
        if constexpr (EPI == 0) {
          v += bias[cg];
          if (cg < CD) out0[(size_t)rg*CD + cg] = v;
          else         out1[(size_t)rg*CD + cg - CD] = v;
        } else if constexpr (EPI == 1) {
          int p = rg % HWS;
          float u  = Uin[(size_t)rg*CD + cg];
          float cd = cosD[(size_t)p*CD + cg];
          float sd = sinD[(size_t)p*CD + cg];
          if (p == 0) v += 56.f * velb[cg];
          out0[(size_t)rg*CD + cg] = cd*u + sd*(v + ahalf*u);
        } else {
          v += bias[cg];
          int bidx = rg / HWS, hw = rg % HWS;
          out0[((size_t)bidx*CD + cg)*HWS + hw] = v;
        }
      }
    }
  }
}

// ---------------- batched 56x56 DCT-matrix apply ------------------------------
__global__ __launch_bounds__(448) void dct_k(
    const float* __restrict__ in, float* __restrict__ out,
    const float* __restrict__ D, int NC, int trans)
{
  __shared__ float Ds[56][60];
  __shared__ float Xs[56][128];
  int t = threadIdx.x;
  int c0 = blockIdx.x * 128;
  size_t bt = blockIdx.y;
  for (int idx = t; idx < 3136; idx += 448) {
    int k = idx / 56, m = idx % 56;
    Ds[k][m] = trans ? D[k*56 + m] : D[m*56 + k];
  }
  const float* inb = in + bt*56*(size_t)NC + c0;
  for (int fi = t; fi < 56*32; fi += 448) {
    int rw = fi >> 5, cg = fi & 31;
    *(float4*)&Xs[rw][cg*4] = *(const float4*)(inb + (size_t)rw*NC + cg*4);
  }
  __syncthreads();
  int tx = t % 32, ty = t / 32;
  float acc[4][4] = {};
  #pragma unroll 4
  for (int k = 0; k < 56; ++k) {
    float4 a4 = *(const float4*)&Ds[k][ty*4];
    float4 b4 = *(const float4*)&Xs[k][tx*4];
    float aa[4] = {a4.x, a4.y, a4.z, a4.w};
    float bbv[4] = {b4.x, b4.y, b4.z, b4.w};
    #pragma unroll
    for (int i = 0; i < 4; ++i)
      #pragma unroll
      for (int j = 0; j < 4; ++j)
        acc[i][j] = fmaf(aa[i], bbv[j], acc[i][j]);
  }
  float* ob = out + bt*56*(size_t)NC + c0;
  #pragma unroll
  for (int i = 0; i < 4; ++i) {
    int m = ty*4 + i;
    float4 o; o.x = acc[i][0]; o.y = acc[i][1]; o.z = acc[i][2]; o.w = acc[i][3];
    *(float4*)(ob + (size_t)m*NC + tx*4) = o;
  }
}

// ---------------- LayerNorm over C + SiLU gate --------------------------------
__global__ __launch_bounds__(256) void ln_gate_k(
    const float* __restrict__ Y, const float* __restrict__ Z,
    const float* __restrict__ g, const float* __restrict__ be,
    float* __restrict__ out)
{
  int lane = threadIdx.x & 63, wv = threadIdx.x >> 6;
  size_t r = (size_t)blockIdx.x*4 + wv;
  const float* y = Y + r*CD;
  float v[6];
  float s = 0.f;
  #pragma unroll
  for (int q = 0; q < 6; ++q) { v[q] = y[lane + 64*q]; s += v[q]; }
  #pragma unroll
  for (int off = 32; off > 0; off >>= 1) s += __shfl_xor(s, off, 64);
  float mu = s * (1.f/384.f);
  float s2 = 0.f;
  #pragma unroll
  for (int q = 0; q < 6; ++q) { float d = v[q]-mu; s2 += d*d; }
  #pragma unroll
  for (int off = 32; off > 0; off >>= 1) s2 += __shfl_xor(s2, off, 64);
  float rs = 1.f / sqrtf(s2*(1.f/384.f) + 1e-5f);
  #pragma unroll
  for (int q = 0; q < 6; ++q) {
    int c = lane + 64*q;
    float yn = (v[q]-mu)*rs*g[c] + be[c];
    float zv = Z[r*CD + c];
    float sz = zv / (1.f + expf(-zv));
    out[r*CD + c] = yn*sz;
  }
}

extern "C" void kernel_launch(void* const* d_in, const int* in_sizes, int n_in,
                              void* d_out, int out_size, void* d_ws, size_t ws_size,
                              hipStream_t stream) {
  const float* x     = (const float*)d_in[0];
  const float* fe    = (const float*)d_in[1];
  const float* dw_w  = (const float*)d_in[2];
  const float* dw_b  = (const float*)d_in[3];
  const float* lin_w = (const float*)d_in[4];
  const float* lin_b = (const float*)d_in[5];
  const float* vel_w = (const float*)d_in[6];
  const float* vel_b = (const float*)d_in[7];
  const float* tok_w = (const float*)d_in[8];
  const float* tok_b = (const float*)d_in[9];
  const float* ln_g  = (const float*)d_in[10];
  const float* ln_b  = (const float*)d_in[11];
  const float* out_w = (const float*)d_in[12];
  const float* out_b = (const float*)d_in[13];
  const float* cp    = (const float*)d_in[14];
  const float* ap    = (const float*)d_in[15];

  float* ws    = (float*)d_ws;
  float* slotA = ws;                 // xc -> Tu -> F -> Y
  float* slotB = ws + SLOT;          // xg -> U -> G -> gated
  float* slotC = ws + 2*SLOT;        // z
  float* Dm    = ws + 3*SLOT;
  float* cosD  = Dm + 3136;
  float* sinD  = cosD + (size_t)HWS*CD;
  ushort* whi  = (ushort*)(sinD + (size_t)HWS*CD);
  ushort* wlo  = whi + 589824;

  prep_d_k<<<1, 256, 0, stream>>>(Dm);
  split_w_k<<<1152, 256, 0, stream>>>(lin_w, whi,          wlo,          294912);
  split_w_k<<< 576, 256, 0, stream>>>(vel_w, whi + 294912, wlo + 294912, 147456);
  split_w_k<<< 576, 256, 0, stream>>>(out_w, whi + 442368, wlo + 442368, 147456);

  // conv(x) -> channel-last xc (slotA)
  conv_k<<<dim3(12, 56, 16), 256, 0, stream>>>(x, dw_w, dw_b, slotA);
  // tok path: cos/sin*decay maps
  gemm_k<2><<<dim3(6, 49), 256, 0, stream>>>(fe, tok_w, tok_b, cosD, sinD, cp);
  // lin: xz = xc @ lin_w^T + lin_b -> xg (slotB), z (slotC)
  mgemm_k<0><<<dim3(6, 392), 256, 0, stream>>>(slotA, whi, wlo, lin_b,
      slotB, slotC, nullptr, nullptr, nullptr, nullptr, nullptr);
  // forward DCT
  dct_k<<<dim3(168, 16), 448, 0, stream>>>(slotB, slotA, Dm, 21504, 0); // Tu -> slotA
  dct_k<<<dim3(3, 896), 448, 0, stream>>>(slotA, slotB, Dm, 384, 0);    // U  -> slotB
  // vel in freq domain + fused modulation -> F (slotA)
  mgemm_k<1><<<dim3(3, 392), 256, 0, stream>>>(slotB, whi + 294912, wlo + 294912,
      nullptr, slotA, nullptr, slotB, cosD, sinD, vel_b, ap);
  // inverse DCT
  dct_k<<<dim3(168, 16), 448, 0, stream>>>(slotA, slotB, Dm, 21504, 1); // G -> slotB
  dct_k<<<dim3(3, 896), 448, 0, stream>>>(slotB, slotA, Dm, 384, 1);    // Y -> slotA
  // LayerNorm + SiLU gate -> gated (slotB)
  ln_gate_k<<<12544, 256, 0, stream>>>(slotA, slotC, ln_g, ln_b, slotB);
  // out GEMM -> d_out [B,C,H,W]
  mgemm_k<3><<<dim3(3, 392), 256, 0, stream>>>(slotB, whi + 442368, wlo + 442368,
      out_b, (float*)d_out, nullptr, nullptr, nullptr, nullptr, nullptr, nullptr);
}